// Round 1
// baseline (560.804 us; speedup 1.0000x reference)
//
#include <hip/hip_runtime.h>
#include <math.h>

#define BROWS 65536
#define DIMS 512
#define NCLS 256
#define MARGIN 0.3f
#define EPSN 1e-12f

__device__ __forceinline__ float waveReduceSum(float v) {
  for (int off = 32; off > 0; off >>= 1) v += __shfl_down(v, off, 64);
  return v;
}

// Kernel A: per-row inverse norm (1/max(||x||,eps)) + per-class counts.
__global__ void __launch_bounds__(256) knorm(const float* __restrict__ emb,
                                             const int* __restrict__ labels,
                                             float* __restrict__ invnorm,
                                             float* __restrict__ counts) {
  int gid = blockIdx.x * blockDim.x + threadIdx.x;
  int wave = gid >> 6, lane = gid & 63;
  int nw = (gridDim.x * blockDim.x) >> 6;
  for (int r = wave; r < BROWS; r += nw) {
    const float4* row = reinterpret_cast<const float4*>(emb + (size_t)r * DIMS);
    float4 a = row[lane * 2];
    float4 b = row[lane * 2 + 1];
    float s = a.x*a.x + a.y*a.y + a.z*a.z + a.w*a.w
            + b.x*b.x + b.y*b.y + b.z*b.z + b.w*b.w;
    s = waveReduceSum(s);
    if (lane == 0) {
      invnorm[r] = 1.0f / fmaxf(sqrtf(s), EPSN);
      unsafeAtomicAdd(&counts[labels[r]], 1.0f);
    }
  }
}

// Kernel B: per-class segment sum of normalized embeddings.
// Grid = nchunk*8 blocks; block (chunk, slice) accumulates a 64-col slice of
// rows [chunk*rpc, (chunk+1)*rpc) into LDS [256 classes][64 cols] (64 KB),
// then writes its partial to partials[chunk][cls][512] (no global atomics).
__global__ void __launch_bounds__(256) ksegsum(const float* __restrict__ emb,
                                               const int* __restrict__ labels,
                                               const float* __restrict__ invnorm,
                                               float* __restrict__ partials,
                                               int rowsPerChunk) {
  __shared__ float acc[NCLS * 64];
  int chunk = blockIdx.x >> 3, slice = blockIdx.x & 7;
  int t = threadIdx.x;
  for (int i = t; i < NCLS * 64; i += 256) acc[i] = 0.0f;
  __syncthreads();
  int r0 = chunk * rowsPerChunk;
  int col0 = slice * 64;
  int rsub = t >> 4;            // 16 rows in flight
  int c4 = (t & 15) * 4;        // 16 threads x float4 = 64 cols
  for (int r = r0 + rsub; r < r0 + rowsPerChunk; r += 16) {
    int lab = labels[r];
    float inv = invnorm[r];
    float4 v = *reinterpret_cast<const float4*>(emb + (size_t)r * DIMS + col0 + c4);
    float* dst = &acc[lab * 64 + c4];
    unsafeAtomicAdd(dst + 0, v.x * inv);
    unsafeAtomicAdd(dst + 1, v.y * inv);
    unsafeAtomicAdd(dst + 2, v.z * inv);
    unsafeAtomicAdd(dst + 3, v.w * inv);
  }
  __syncthreads();
  float* out = partials + (size_t)chunk * NCLS * DIMS;
  for (int i = t; i < NCLS * 64; i += 256) {
    int cls = i >> 6, c = i & 63;
    out[(size_t)cls * DIMS + col0 + c] = acc[i];
  }
}

// Kernel C: reduce partials -> mean -> L2-normalized centroid. 1 block/class.
__global__ void __launch_bounds__(256) kcent(const float* __restrict__ partials,
                                             const float* __restrict__ counts,
                                             float* __restrict__ cent, int nchunk) {
  int cls = blockIdx.x, t = threadIdx.x;  // 256 threads, 2 cols each
  float s0 = 0.0f, s1 = 0.0f;
  for (int ch = 0; ch < nchunk; ++ch) {
    const float* p = partials + (size_t)ch * NCLS * DIMS + (size_t)cls * DIMS;
    s0 += p[t];
    s1 += p[t + 256];
  }
  float cm = fmaxf(counts[cls], 1.0f);
  float m0 = s0 / cm, m1 = s1 / cm;
  __shared__ float red[256];
  red[t] = m0 * m0 + m1 * m1;
  __syncthreads();
  for (int off = 128; off > 0; off >>= 1) {
    if (t < off) red[t] += red[t + off];
    __syncthreads();
  }
  float inv = 1.0f / fmaxf(sqrtf(red[0]), EPSN);
  cent[(size_t)cls * DIMS + t] = m0 * inv;
  cent[(size_t)cls * DIMS + t + 256] = m1 * inv;
}

// Kernel D: nearest-centroid argmin with diag + absent-class masking.
// Lexicographic (dist, idx) reduce to match jnp.argmin tie-breaking.
__global__ void __launch_bounds__(256) knearest(const float* __restrict__ cent,
                                                const float* __restrict__ counts,
                                                int* __restrict__ nearest) {
  int i = blockIdx.x, j = threadIdx.x;
  __shared__ float ci[DIMS];
  ci[j] = cent[(size_t)i * DIMS + j];
  ci[j + 256] = cent[(size_t)i * DIMS + j + 256];
  __syncthreads();
  const float4* cj = reinterpret_cast<const float4*>(cent + (size_t)j * DIMS);
  float dot = 0.0f;
#pragma unroll 8
  for (int k = 0; k < DIMS / 4; ++k) {
    float4 v = cj[k];
    dot += v.x * ci[4*k] + v.y * ci[4*k+1] + v.z * ci[4*k+2] + v.w * ci[4*k+3];
  }
  float dist = sqrtf(fmaxf(2.0f - 2.0f * dot, 0.0f));
  bool valid = (j != i) && (counts[j] > 0.0f);
  float dv = valid ? dist : INFINITY;
  __shared__ float sd[256];
  __shared__ int si[256];
  sd[j] = dv; si[j] = j;
  __syncthreads();
  for (int off = 128; off > 0; off >>= 1) {
    if (j < off) {
      float o = sd[j + off]; int oi = si[j + off];
      if (o < sd[j] || (o == sd[j] && oi < si[j])) { sd[j] = o; si[j] = oi; }
    }
    __syncthreads();
  }
  if (j == 0) nearest[i] = si[0];
}

// Kernel E: per-row triplet term, accumulate into per-class loss sums.
// d_pos - d_neg = dot(emb_norm, neg_c - pos_c); term = relu(that + margin).
__global__ void __launch_bounds__(256) kterms(const float* __restrict__ emb,
                                              const int* __restrict__ labels,
                                              const float* __restrict__ invnorm,
                                              const float* __restrict__ cent,
                                              const int* __restrict__ nearest,
                                              float* __restrict__ loss_c) {
  int gid = blockIdx.x * blockDim.x + threadIdx.x;
  int wave = gid >> 6, lane = gid & 63;
  int nw = (gridDim.x * blockDim.x) >> 6;
  for (int r = wave; r < BROWS; r += nw) {
    int lab = labels[r];
    int ng = nearest[lab];
    const float4* row = reinterpret_cast<const float4*>(emb + (size_t)r * DIMS);
    const float4* pc = reinterpret_cast<const float4*>(cent + (size_t)lab * DIMS);
    const float4* nc = reinterpret_cast<const float4*>(cent + (size_t)ng * DIMS);
    float4 a = row[2*lane], b = row[2*lane+1];
    float4 p = pc[2*lane],  q = pc[2*lane+1];
    float4 u = nc[2*lane],  w = nc[2*lane+1];
    float s = a.x*(u.x-p.x) + a.y*(u.y-p.y) + a.z*(u.z-p.z) + a.w*(u.w-p.w)
            + b.x*(w.x-q.x) + b.y*(w.y-q.y) + b.z*(w.z-q.z) + b.w*(w.w-q.w);
    s = waveReduceSum(s);
    if (lane == 0) {
      float term = fmaxf(s * invnorm[r] + MARGIN, 0.0f);
      unsafeAtomicAdd(&loss_c[lab], term);
    }
  }
}

// Kernel F: final present-masked mean of per-class means.
__global__ void __launch_bounds__(256) kfinal(const float* __restrict__ counts,
                                              const float* __restrict__ loss_c,
                                              float* __restrict__ out) {
  int t = threadIdx.x;
  float cnt = counts[t];
  bool present = cnt > 0.0f;
  float v = present ? loss_c[t] / fmaxf(cnt, 1.0f) : 0.0f;
  float np = present ? 1.0f : 0.0f;
  __shared__ float sv[256], sp[256];
  sv[t] = v; sp[t] = np;
  __syncthreads();
  for (int off = 128; off > 0; off >>= 1) {
    if (t < off) { sv[t] += sv[t + off]; sp[t] += sp[t + off]; }
    __syncthreads();
  }
  if (t == 0) out[0] = sv[0] / fmaxf(sp[0], 1.0f);
}

extern "C" void kernel_launch(void* const* d_in, const int* in_sizes, int n_in,
                              void* d_out, int out_size, void* d_ws, size_t ws_size,
                              hipStream_t stream) {
  const float* emb = (const float*)d_in[0];
  const int* labels = (const int*)d_in[1];
  float* out = (float*)d_out;

  char* ws = (char*)d_ws;
  size_t off = 0;
  auto alloc = [&](size_t bytes) {
    char* p = ws + off;
    off += (bytes + 255) & ~(size_t)255;
    return p;
  };
  float* invnorm = (float*)alloc((size_t)BROWS * 4);          // 256 KB
  float* counts  = (float*)alloc((size_t)NCLS * 4);           // 1 KB
  float* loss_c  = (float*)alloc((size_t)NCLS * 4);           // 1 KB (contiguous after counts)
  float* cent    = (float*)alloc((size_t)NCLS * DIMS * 4);    // 512 KB
  int*   nearest = (int*)alloc((size_t)NCLS * 4);             // 1 KB
  size_t fixed = off;

  int nchunk = 64;  // partials: nchunk * 512 KB
  while (nchunk > 1 && fixed + (size_t)nchunk * NCLS * DIMS * 4 > ws_size) nchunk >>= 1;
  float* partials = (float*)alloc((size_t)nchunk * NCLS * DIMS * 4);
  int rowsPerChunk = BROWS / nchunk;

  // counts and loss_c are adjacent 1 KB regions -> one 2 KB memset.
  hipMemsetAsync(counts, 0, 2 * NCLS * sizeof(float), stream);

  knorm<<<2048, 256, 0, stream>>>(emb, labels, invnorm, counts);
  ksegsum<<<nchunk * 8, 256, 0, stream>>>(emb, labels, invnorm, partials, rowsPerChunk);
  kcent<<<NCLS, 256, 0, stream>>>(partials, counts, cent, nchunk);
  knearest<<<NCLS, 256, 0, stream>>>(cent, counts, nearest);
  kterms<<<2048, 256, 0, stream>>>(emb, labels, invnorm, cent, nearest, loss_c);
  kfinal<<<1, 256, 0, stream>>>(counts, loss_c, out);
}

// Round 3
// 429.176 us; speedup vs baseline: 1.3067x; 1.3067x over previous
//
#include <hip/hip_runtime.h>
#include <math.h>

#define BROWS 65536
#define DIMS 512
#define NCLS 256
#define MARGIN 0.3f
#define EPSN 1e-12f
#define SPLITS 4

__device__ __forceinline__ float waveReduceSum(float v) {
  for (int off = 32; off > 0; off >>= 1) v += __shfl_down(v, off, 64);
  return v;
}

// Kernel A: per-row inverse norm (1/max(||x||,eps)) + per-class counts.
__global__ void __launch_bounds__(256) knorm(const float* __restrict__ emb,
                                             const int* __restrict__ labels,
                                             float* __restrict__ invnorm,
                                             float* __restrict__ counts) {
  int gid = blockIdx.x * blockDim.x + threadIdx.x;
  int wave = gid >> 6, lane = gid & 63;
  int nw = (gridDim.x * blockDim.x) >> 6;
  for (int r = wave; r < BROWS; r += nw) {
    const float4* row = reinterpret_cast<const float4*>(emb + (size_t)r * DIMS);
    float4 a = row[lane * 2];
    float4 b = row[lane * 2 + 1];
    float s = a.x*a.x + a.y*a.y + a.z*a.z + a.w*a.w
            + b.x*b.x + b.y*b.y + b.z*b.z + b.w*b.w;
    s = waveReduceSum(s);
    if (lane == 0) {
      invnorm[r] = 1.0f / fmaxf(sqrtf(s), EPSN);
      unsafeAtomicAdd(&counts[labels[r]], 1.0f);
    }
  }
}

// Kernel B1: exclusive scan of counts -> bases; init cursor = bases.
__global__ void __launch_bounds__(256) kbase(const float* __restrict__ counts,
                                             int* __restrict__ bases,
                                             int* __restrict__ cursor) {
  int t = threadIdx.x;
  __shared__ int sc[NCLS];
  sc[t] = (int)counts[t];
  __syncthreads();
  // simple inclusive scan (Hillis-Steele), then shift to exclusive
  int v = sc[t];
  for (int off = 1; off < NCLS; off <<= 1) {
    int add = (t >= off) ? sc[t - off] : 0;
    __syncthreads();
    sc[t] = v = v + add;
    __syncthreads();
  }
  int excl = (t == 0) ? 0 : sc[t - 1];
  bases[t] = excl;
  cursor[t] = excl;
}

// Kernel B2: counting-sort scatter of row indices by label.
__global__ void __launch_bounds__(256) kscatter(const int* __restrict__ labels,
                                                int* __restrict__ cursor,
                                                int* __restrict__ rowidx) {
  int r = blockIdx.x * blockDim.x + threadIdx.x;
  int lab = labels[r];
  int pos = atomicAdd(&cursor[lab], 1);
  rowidx[pos] = r;
}

// Kernel B3: per-class segment sum via sorted row list, register accumulate.
// Grid = NCLS * SPLITS blocks. Block (c, s) sums a slice of class c's rows.
// rowidx entries are block-uniform -> scalar loads; emb reads fully coalesced.
__global__ void __launch_bounds__(256) ksum(const float* __restrict__ emb,
                                            const float* __restrict__ invnorm,
                                            const int* __restrict__ rowidx,
                                            const int* __restrict__ bases,
                                            const float* __restrict__ counts,
                                            float* __restrict__ partials) {
  int cls = blockIdx.x >> 2, sp = blockIdx.x & (SPLITS - 1);
  int t = threadIdx.x;
  int base = bases[cls];
  int cnt = (int)counts[cls];
  int i0 = (cnt * sp) / SPLITS, i1 = (cnt * (sp + 1)) / SPLITS;
  float s0 = 0.0f, s1 = 0.0f;
  int i = i0;
  for (; i + 2 <= i1; i += 2) {
    int ra = rowidx[base + i], rb = rowidx[base + i + 1];
    float ia = invnorm[ra], ib = invnorm[rb];
    const float* pa = emb + (size_t)ra * DIMS;
    const float* pb = emb + (size_t)rb * DIMS;
    float a0 = pa[t], a1 = pa[t + 256];
    float b0 = pb[t], b1 = pb[t + 256];
    s0 += a0 * ia + b0 * ib;
    s1 += a1 * ia + b1 * ib;
  }
  if (i < i1) {
    int ra = rowidx[base + i];
    float ia = invnorm[ra];
    const float* pa = emb + (size_t)ra * DIMS;
    s0 += pa[t] * ia;
    s1 += pa[t + 256] * ia;
  }
  float* out = partials + ((size_t)sp * NCLS + cls) * DIMS;
  out[t] = s0;
  out[t + 256] = s1;
}

// Kernel C: reduce partials -> mean -> L2-normalized centroid. 1 block/class.
__global__ void __launch_bounds__(256) kcent(const float* __restrict__ partials,
                                             const float* __restrict__ counts,
                                             float* __restrict__ cent) {
  int cls = blockIdx.x, t = threadIdx.x;  // 256 threads, 2 cols each
  float s0 = 0.0f, s1 = 0.0f;
#pragma unroll
  for (int sp = 0; sp < SPLITS; ++sp) {
    const float* p = partials + ((size_t)sp * NCLS + cls) * DIMS;
    s0 += p[t];
    s1 += p[t + 256];
  }
  float cm = fmaxf(counts[cls], 1.0f);
  float m0 = s0 / cm, m1 = s1 / cm;
  __shared__ float red[256];
  red[t] = m0 * m0 + m1 * m1;
  __syncthreads();
  for (int off = 128; off > 0; off >>= 1) {
    if (t < off) red[t] += red[t + off];
    __syncthreads();
  }
  float inv = 1.0f / fmaxf(sqrtf(red[0]), EPSN);
  cent[(size_t)cls * DIMS + t] = m0 * inv;
  cent[(size_t)cls * DIMS + t + 256] = m1 * inv;
}

// Kernel D: nearest-centroid argmin with diag + absent-class masking.
__global__ void __launch_bounds__(256) knearest(const float* __restrict__ cent,
                                                const float* __restrict__ counts,
                                                int* __restrict__ nearest) {
  int i = blockIdx.x, j = threadIdx.x;
  __shared__ float ci[DIMS];
  ci[j] = cent[(size_t)i * DIMS + j];
  ci[j + 256] = cent[(size_t)i * DIMS + j + 256];
  __syncthreads();
  const float4* cj = reinterpret_cast<const float4*>(cent + (size_t)j * DIMS);
  float dot = 0.0f;
#pragma unroll 8
  for (int k = 0; k < DIMS / 4; ++k) {
    float4 v = cj[k];
    dot += v.x * ci[4*k] + v.y * ci[4*k+1] + v.z * ci[4*k+2] + v.w * ci[4*k+3];
  }
  float dist = sqrtf(fmaxf(2.0f - 2.0f * dot, 0.0f));
  bool valid = (j != i) && (counts[j] > 0.0f);
  float dv = valid ? dist : INFINITY;
  __shared__ float sd[256];
  __shared__ int si[256];
  sd[j] = dv; si[j] = j;
  __syncthreads();
  for (int off = 128; off > 0; off >>= 1) {
    if (j < off) {
      float o = sd[j + off]; int oi = si[j + off];
      if (o < sd[j] || (o == sd[j] && oi < si[j])) { sd[j] = o; si[j] = oi; }
    }
    __syncthreads();
  }
  if (j == 0) nearest[i] = si[0];
}

// Kernel E: per-row triplet term, accumulate into per-class loss sums.
__global__ void __launch_bounds__(256) kterms(const float* __restrict__ emb,
                                              const int* __restrict__ labels,
                                              const float* __restrict__ invnorm,
                                              const float* __restrict__ cent,
                                              const int* __restrict__ nearest,
                                              float* __restrict__ loss_c) {
  int gid = blockIdx.x * blockDim.x + threadIdx.x;
  int wave = gid >> 6, lane = gid & 63;
  int nw = (gridDim.x * blockDim.x) >> 6;
  for (int r = wave; r < BROWS; r += nw) {
    int lab = labels[r];
    int ng = nearest[lab];
    const float4* row = reinterpret_cast<const float4*>(emb + (size_t)r * DIMS);
    const float4* pc = reinterpret_cast<const float4*>(cent + (size_t)lab * DIMS);
    const float4* nc = reinterpret_cast<const float4*>(cent + (size_t)ng * DIMS);
    float4 a = row[2*lane], b = row[2*lane+1];
    float4 p = pc[2*lane],  q = pc[2*lane+1];
    float4 u = nc[2*lane],  w = nc[2*lane+1];
    float s = a.x*(u.x-p.x) + a.y*(u.y-p.y) + a.z*(u.z-p.z) + a.w*(u.w-p.w)
            + b.x*(w.x-q.x) + b.y*(w.y-q.y) + b.z*(w.z-q.z) + b.w*(w.w-q.w);
    s = waveReduceSum(s);
    if (lane == 0) {
      float term = fmaxf(s * invnorm[r] + MARGIN, 0.0f);
      unsafeAtomicAdd(&loss_c[lab], term);
    }
  }
}

// Kernel F: final present-masked mean of per-class means.
__global__ void __launch_bounds__(256) kfinal(const float* __restrict__ counts,
                                              const float* __restrict__ loss_c,
                                              float* __restrict__ out) {
  int t = threadIdx.x;
  float cnt = counts[t];
  bool present = cnt > 0.0f;
  float v = present ? loss_c[t] / fmaxf(cnt, 1.0f) : 0.0f;
  float np = present ? 1.0f : 0.0f;
  __shared__ float sv[256], sp[256];
  sv[t] = v; sp[t] = np;
  __syncthreads();
  for (int off = 128; off > 0; off >>= 1) {
    if (t < off) { sv[t] += sv[t + off]; sp[t] += sp[t + off]; }
    __syncthreads();
  }
  if (t == 0) out[0] = sv[0] / fmaxf(sp[0], 1.0f);
}

extern "C" void kernel_launch(void* const* d_in, const int* in_sizes, int n_in,
                              void* d_out, int out_size, void* d_ws, size_t ws_size,
                              hipStream_t stream) {
  const float* emb = (const float*)d_in[0];
  const int* labels = (const int*)d_in[1];
  float* out = (float*)d_out;

  char* ws = (char*)d_ws;
  size_t off = 0;
  auto alloc = [&](size_t bytes) {
    char* p = ws + off;
    off += (bytes + 255) & ~(size_t)255;
    return p;
  };
  float* invnorm = (float*)alloc((size_t)BROWS * 4);               // 256 KB
  float* counts  = (float*)alloc((size_t)NCLS * 4);                // 1 KB
  float* loss_c  = (float*)alloc((size_t)NCLS * 4);                // 1 KB (adjacent)
  float* cent    = (float*)alloc((size_t)NCLS * DIMS * 4);         // 512 KB
  int*   nearest = (int*)alloc((size_t)NCLS * 4);                  // 1 KB
  int*   bases   = (int*)alloc((size_t)NCLS * 4);                  // 1 KB
  int*   cursor  = (int*)alloc((size_t)NCLS * 4);                  // 1 KB
  int*   rowidx  = (int*)alloc((size_t)BROWS * 4);                 // 256 KB
  float* partials= (float*)alloc((size_t)SPLITS * NCLS * DIMS * 4);// 2 MB

  // counts and loss_c are adjacent 1 KB regions -> one 2 KB memset.
  hipMemsetAsync(counts, 0, 2 * NCLS * sizeof(float), stream);

  knorm<<<2048, 256, 0, stream>>>(emb, labels, invnorm, counts);
  kbase<<<1, 256, 0, stream>>>(counts, bases, cursor);
  kscatter<<<BROWS / 256, 256, 0, stream>>>(labels, cursor, rowidx);
  ksum<<<NCLS * SPLITS, 256, 0, stream>>>(emb, invnorm, rowidx, bases, counts, partials);
  kcent<<<NCLS, 256, 0, stream>>>(partials, counts, cent);
  knearest<<<NCLS, 256, 0, stream>>>(cent, counts, nearest);
  kterms<<<2048, 256, 0, stream>>>(emb, labels, invnorm, cent, nearest, loss_c);
  kfinal<<<1, 256, 0, stream>>>(counts, loss_c, out);
}

// Round 4
// 258.383 us; speedup vs baseline: 2.1704x; 1.6610x over previous
//
#include <hip/hip_runtime.h>
#include <math.h>

#define BROWS 65536
#define DIMS 512
#define NCLS 256
#define MARGIN 0.3f
#define EPSN 1e-12f
#define TSPL 8      // kterm2 splits per class
#define CURPAD 16   // cursor stride in ints (64 B) -> atomics spread over L2 lines

// Kernel H: label histogram -> counts (float). 32 blocks x 256 thr x 8 labels.
__global__ void __launch_bounds__(256) khist(const int* __restrict__ labels,
                                             float* __restrict__ counts) {
  __shared__ int h[NCLS];
  int t = threadIdx.x;
  h[t] = 0;
  __syncthreads();
  int base = blockIdx.x * 2048 + t;
#pragma unroll
  for (int k = 0; k < 8; ++k) atomicAdd(&h[labels[base + k * 256]], 1);
  __syncthreads();
  if (h[t] > 0) unsafeAtomicAdd(&counts[t], (float)h[t]);
}

// Kernel B1: exclusive scan of counts -> bases; init padded cursor.
__global__ void __launch_bounds__(256) kbase(const float* __restrict__ counts,
                                             int* __restrict__ bases,
                                             int* __restrict__ cursor) {
  int t = threadIdx.x;
  __shared__ int sc[NCLS];
  sc[t] = (int)counts[t];
  __syncthreads();
  int v = sc[t];
  for (int off = 1; off < NCLS; off <<= 1) {
    int add = (t >= off) ? sc[t - off] : 0;
    __syncthreads();
    sc[t] = v = v + add;
    __syncthreads();
  }
  int excl = (t == 0) ? 0 : sc[t - 1];
  bases[t] = excl;
  cursor[t * CURPAD] = excl;
}

// Kernel B2: counting-sort scatter of row indices by label (padded cursors).
__global__ void __launch_bounds__(256) kscatter(const int* __restrict__ labels,
                                                int* __restrict__ cursor,
                                                int* __restrict__ rowidx) {
  int r = blockIdx.x * blockDim.x + threadIdx.x;
  int lab = labels[r];
  int pos = atomicAdd(&cursor[lab * CURPAD], 1);
  rowidx[pos] = r;
}

// Kernel S: fused row-norm + per-class segment sum of normalized rows.
// Wave holds the full 512-dim partial centroid in 8 VGPRs/lane; 4-row unroll
// puts 8 independent dwordx4 loads in flight per iteration.
__global__ void __launch_bounds__(256) ksumn(const float* __restrict__ emb,
                                             const int* __restrict__ rowidx,
                                             const int* __restrict__ bases,
                                             const float* __restrict__ counts,
                                             float* __restrict__ invnorm,
                                             float* __restrict__ partials,
                                             int lsplits) {
  int splits = 1 << lsplits;
  int cls = blockIdx.x >> lsplits;
  int sp = blockIdx.x & (splits - 1);
  int t = threadIdx.x, w = t >> 6, lane = t & 63;
  int base = bases[cls];
  int cnt = (int)counts[cls];
  int i0 = (cnt * sp) >> lsplits;
  int i1 = (cnt * (sp + 1)) >> lsplits;
  int n = i1 - i0;
  int j0 = i0 + ((n * w) >> 2);
  int j1 = i0 + ((n * (w + 1)) >> 2);
  const float4* ebase = reinterpret_cast<const float4*>(emb);
  int cq = lane * 2;  // float4 index of this lane's 32B column chunk
  float4 acc0 = make_float4(0.f, 0.f, 0.f, 0.f);
  float4 acc1 = make_float4(0.f, 0.f, 0.f, 0.f);
  int j = j0;
  for (; j + 4 <= j1; j += 4) {
    int r[4];
#pragma unroll
    for (int k = 0; k < 4; ++k) r[k] = rowidx[base + j + k];
    float4 a[4], b[4];
#pragma unroll
    for (int k = 0; k < 4; ++k) {
      const float4* p = ebase + (size_t)r[k] * (DIMS / 4) + cq;
      a[k] = p[0];
      b[k] = p[1];
    }
    float s[4];
#pragma unroll
    for (int k = 0; k < 4; ++k)
      s[k] = a[k].x*a[k].x + a[k].y*a[k].y + a[k].z*a[k].z + a[k].w*a[k].w
           + b[k].x*b[k].x + b[k].y*b[k].y + b[k].z*b[k].z + b[k].w*b[k].w;
#pragma unroll
    for (int off = 1; off < 64; off <<= 1) {
#pragma unroll
      for (int k = 0; k < 4; ++k) s[k] += __shfl_xor(s[k], off, 64);
    }
    float q[4];
#pragma unroll
    for (int k = 0; k < 4; ++k) q[k] = 1.0f / fmaxf(sqrtf(s[k]), EPSN);
    if (lane == 0) {
      invnorm[r[0]] = q[0]; invnorm[r[1]] = q[1];
      invnorm[r[2]] = q[2]; invnorm[r[3]] = q[3];
    }
#pragma unroll
    for (int k = 0; k < 4; ++k) {
      acc0.x += a[k].x * q[k]; acc0.y += a[k].y * q[k];
      acc0.z += a[k].z * q[k]; acc0.w += a[k].w * q[k];
      acc1.x += b[k].x * q[k]; acc1.y += b[k].y * q[k];
      acc1.z += b[k].z * q[k]; acc1.w += b[k].w * q[k];
    }
  }
  for (; j < j1; ++j) {
    int r0 = rowidx[base + j];
    const float4* p = ebase + (size_t)r0 * (DIMS / 4) + cq;
    float4 a = p[0], b = p[1];
    float s = a.x*a.x + a.y*a.y + a.z*a.z + a.w*a.w
            + b.x*b.x + b.y*b.y + b.z*b.z + b.w*b.w;
#pragma unroll
    for (int off = 1; off < 64; off <<= 1) s += __shfl_xor(s, off, 64);
    float q0 = 1.0f / fmaxf(sqrtf(s), EPSN);
    if (lane == 0) invnorm[r0] = q0;
    acc0.x += a.x * q0; acc0.y += a.y * q0; acc0.z += a.z * q0; acc0.w += a.w * q0;
    acc1.x += b.x * q0; acc1.y += b.y * q0; acc1.z += b.z * q0; acc1.w += b.w * q0;
  }
  __shared__ float lds[4][DIMS];
  *reinterpret_cast<float4*>(&lds[w][lane * 8]) = acc0;
  *reinterpret_cast<float4*>(&lds[w][lane * 8 + 4]) = acc1;
  __syncthreads();
  float o0 = lds[0][t] + lds[1][t] + lds[2][t] + lds[3][t];
  float o1 = lds[0][t + 256] + lds[1][t + 256] + lds[2][t + 256] + lds[3][t + 256];
  float* outp = partials + ((size_t)sp * NCLS + cls) * DIMS;
  outp[t] = o0;
  outp[t + 256] = o1;
}

// Kernel C: reduce split partials -> mean -> L2-normalized centroid.
__global__ void __launch_bounds__(256) kcent(const float* __restrict__ partials,
                                             const float* __restrict__ counts,
                                             float* __restrict__ cent, int splits) {
  int cls = blockIdx.x, t = threadIdx.x;
  float s0 = 0.0f, s1 = 0.0f;
  for (int sp = 0; sp < splits; ++sp) {
    const float* p = partials + ((size_t)sp * NCLS + cls) * DIMS;
    s0 += p[t];
    s1 += p[t + 256];
  }
  float cm = fmaxf(counts[cls], 1.0f);
  float m0 = s0 / cm, m1 = s1 / cm;
  __shared__ float red[256];
  red[t] = m0 * m0 + m1 * m1;
  __syncthreads();
  for (int off = 128; off > 0; off >>= 1) {
    if (t < off) red[t] += red[t + off];
    __syncthreads();
  }
  float inv = 1.0f / fmaxf(sqrtf(red[0]), EPSN);
  cent[(size_t)cls * DIMS + t] = m0 * inv;
  cent[(size_t)cls * DIMS + t + 256] = m1 * inv;
}

// Kernel D: nearest-centroid argmin (lexicographic to match jnp.argmin ties).
__global__ void __launch_bounds__(256) knearest(const float* __restrict__ cent,
                                                const float* __restrict__ counts,
                                                int* __restrict__ nearest) {
  int i = blockIdx.x, j = threadIdx.x;
  __shared__ float ci[DIMS];
  ci[j] = cent[(size_t)i * DIMS + j];
  ci[j + 256] = cent[(size_t)i * DIMS + j + 256];
  __syncthreads();
  const float4* cj = reinterpret_cast<const float4*>(cent + (size_t)j * DIMS);
  float dot = 0.0f;
#pragma unroll 8
  for (int k = 0; k < DIMS / 4; ++k) {
    float4 v = cj[k];
    dot += v.x * ci[4*k] + v.y * ci[4*k+1] + v.z * ci[4*k+2] + v.w * ci[4*k+3];
  }
  float dist = sqrtf(fmaxf(2.0f - 2.0f * dot, 0.0f));
  bool valid = (j != i) && (counts[j] > 0.0f);
  float dv = valid ? dist : INFINITY;
  __shared__ float sd[256];
  __shared__ int si[256];
  sd[j] = dv; si[j] = j;
  __syncthreads();
  for (int off = 128; off > 0; off >>= 1) {
    if (j < off) {
      float o = sd[j + off]; int oi = si[j + off];
      if (o < sd[j] || (o == sd[j] && oi < si[j])) { sd[j] = o; si[j] = oi; }
    }
    __syncthreads();
  }
  if (j == 0) nearest[i] = si[0];
}

// Kernel T: sorted per-class triplet terms. diff = neg_c - pos_c lives in
// registers (block-uniform class); 4-row unroll; one partial write per block.
__global__ void __launch_bounds__(256) kterm2(const float* __restrict__ emb,
                                              const float* __restrict__ invnorm,
                                              const int* __restrict__ rowidx,
                                              const int* __restrict__ bases,
                                              const float* __restrict__ counts,
                                              const float* __restrict__ cent,
                                              const int* __restrict__ nearest,
                                              float* __restrict__ tsums) {
  int cls = blockIdx.x >> 3;           // TSPL == 8
  int sp = blockIdx.x & (TSPL - 1);
  int t = threadIdx.x, w = t >> 6, lane = t & 63;
  int base = bases[cls];
  int cnt = (int)counts[cls];
  int ng = nearest[cls];
  int cq = lane * 2;
  const float4* pp = reinterpret_cast<const float4*>(cent + (size_t)cls * DIMS) + cq;
  const float4* pn = reinterpret_cast<const float4*>(cent + (size_t)ng * DIMS) + cq;
  float4 P0 = pp[0], P1 = pp[1], N0 = pn[0], N1 = pn[1];
  float4 d0 = make_float4(N0.x - P0.x, N0.y - P0.y, N0.z - P0.z, N0.w - P0.w);
  float4 d1 = make_float4(N1.x - P1.x, N1.y - P1.y, N1.z - P1.z, N1.w - P1.w);
  int i0 = (cnt * sp) / TSPL;
  int i1 = (cnt * (sp + 1)) / TSPL;
  int n = i1 - i0;
  int j0 = i0 + ((n * w) >> 2);
  int j1 = i0 + ((n * (w + 1)) >> 2);
  const float4* ebase = reinterpret_cast<const float4*>(emb);
  float tsum = 0.0f;
  int j = j0;
  for (; j + 4 <= j1; j += 4) {
    int r[4];
#pragma unroll
    for (int k = 0; k < 4; ++k) r[k] = rowidx[base + j + k];
    float4 a[4], b[4];
#pragma unroll
    for (int k = 0; k < 4; ++k) {
      const float4* p = ebase + (size_t)r[k] * (DIMS / 4) + cq;
      a[k] = p[0];
      b[k] = p[1];
    }
    float s[4];
#pragma unroll
    for (int k = 0; k < 4; ++k)
      s[k] = a[k].x*d0.x + a[k].y*d0.y + a[k].z*d0.z + a[k].w*d0.w
           + b[k].x*d1.x + b[k].y*d1.y + b[k].z*d1.z + b[k].w*d1.w;
#pragma unroll
    for (int off = 1; off < 64; off <<= 1) {
#pragma unroll
      for (int k = 0; k < 4; ++k) s[k] += __shfl_xor(s[k], off, 64);
    }
#pragma unroll
    for (int k = 0; k < 4; ++k)
      tsum += fmaxf(s[k] * invnorm[r[k]] + MARGIN, 0.0f);
  }
  for (; j < j1; ++j) {
    int r0 = rowidx[base + j];
    const float4* p = ebase + (size_t)r0 * (DIMS / 4) + cq;
    float4 a = p[0], b = p[1];
    float s = a.x*d0.x + a.y*d0.y + a.z*d0.z + a.w*d0.w
            + b.x*d1.x + b.y*d1.y + b.z*d1.z + b.w*d1.w;
#pragma unroll
    for (int off = 1; off < 64; off <<= 1) s += __shfl_xor(s, off, 64);
    tsum += fmaxf(s * invnorm[r0] + MARGIN, 0.0f);
  }
  __shared__ float sred[4];
  if (lane == 0) sred[w] = tsum;
  __syncthreads();
  if (t == 0) tsums[blockIdx.x] = sred[0] + sred[1] + sred[2] + sred[3];
}

// Kernel F: final present-masked mean of per-class means.
__global__ void __launch_bounds__(256) kfinal(const float* __restrict__ counts,
                                              const float* __restrict__ tsums,
                                              float* __restrict__ out) {
  int t = threadIdx.x;
  float cnt = counts[t];
  bool present = cnt > 0.0f;
  float ls = 0.0f;
#pragma unroll
  for (int k = 0; k < TSPL; ++k) ls += tsums[t * TSPL + k];
  float v = present ? ls / fmaxf(cnt, 1.0f) : 0.0f;
  float np = present ? 1.0f : 0.0f;
  __shared__ float sv[256], sp[256];
  sv[t] = v; sp[t] = np;
  __syncthreads();
  for (int off = 128; off > 0; off >>= 1) {
    if (t < off) { sv[t] += sv[t + off]; sp[t] += sp[t + off]; }
    __syncthreads();
  }
  if (t == 0) out[0] = sv[0] / fmaxf(sp[0], 1.0f);
}

extern "C" void kernel_launch(void* const* d_in, const int* in_sizes, int n_in,
                              void* d_out, int out_size, void* d_ws, size_t ws_size,
                              hipStream_t stream) {
  const float* emb = (const float*)d_in[0];
  const int* labels = (const int*)d_in[1];
  float* out = (float*)d_out;

  char* ws = (char*)d_ws;
  size_t off = 0;
  auto alloc = [&](size_t bytes) {
    char* p = ws + off;
    off += (bytes + 255) & ~(size_t)255;
    return p;
  };
  float* invnorm = (float*)alloc((size_t)BROWS * 4);                // 256 KB
  float* counts  = (float*)alloc((size_t)NCLS * 4);                 // 1 KB
  float* cent    = (float*)alloc((size_t)NCLS * DIMS * 4);          // 512 KB
  int*   nearest = (int*)alloc((size_t)NCLS * 4);                   // 1 KB
  int*   bases   = (int*)alloc((size_t)NCLS * 4);                   // 1 KB
  int*   cursor  = (int*)alloc((size_t)NCLS * CURPAD * 4);          // 16 KB
  int*   rowidx  = (int*)alloc((size_t)BROWS * 4);                  // 256 KB
  float* tsums   = (float*)alloc((size_t)NCLS * TSPL * 4);          // 8 KB
  size_t fixed = off;

  int lsplits = 3;  // 8 splits -> 2048 blocks on the big pass
  while (lsplits > 0 &&
         fixed + (((size_t)NCLS * DIMS * 4) << lsplits) > ws_size) lsplits--;
  int splits = 1 << lsplits;
  float* partials = (float*)alloc(((size_t)NCLS * DIMS * 4) << lsplits);

  hipMemsetAsync(counts, 0, NCLS * sizeof(float), stream);

  khist<<<32, 256, 0, stream>>>(labels, counts);
  kbase<<<1, 256, 0, stream>>>(counts, bases, cursor);
  kscatter<<<BROWS / 256, 256, 0, stream>>>(labels, cursor, rowidx);
  ksumn<<<NCLS * splits, 256, 0, stream>>>(emb, rowidx, bases, counts,
                                           invnorm, partials, lsplits);
  kcent<<<NCLS, 256, 0, stream>>>(partials, counts, cent, splits);
  knearest<<<NCLS, 256, 0, stream>>>(cent, counts, nearest);
  kterm2<<<NCLS * TSPL, 256, 0, stream>>>(emb, invnorm, rowidx, bases, counts,
                                          cent, nearest, tsums);
  kfinal<<<1, 256, 0, stream>>>(counts, tsums, out);
}

// Round 8
// 253.048 us; speedup vs baseline: 2.2162x; 1.0211x over previous
//
#include <hip/hip_runtime.h>
#include <math.h>

#define BROWS 65536
#define DIMS 512
#define NCLS 256
#define MARGIN 0.3f
#define EPSN 1e-12f
#define NSTRIP 64      // 64 strips x 1024 rows
#define SROWS 1024
#define LSPL 3         // 8 splits/class in ksumn
#define TSPL 8         // 8 splits/class in kterm2

// ---- bf16 pack/unpack (RNE) ----
__device__ __forceinline__ unsigned pk2(float lo, float hi) {
  unsigned a = __float_as_uint(lo), b = __float_as_uint(hi);
  a = (a + 0x7FFFu + ((a >> 16) & 1u)) >> 16;
  b = (b + 0x7FFFu + ((b >> 16) & 1u)) & 0xFFFF0000u;
  return a | b;
}
__device__ __forceinline__ float uplo(unsigned u) { return __uint_as_float(u << 16); }
__device__ __forceinline__ float uphi(unsigned u) { return __uint_as_float(u & 0xFFFF0000u); }

// K1: per-strip label histogram (LDS atomics only).
__global__ void __launch_bounds__(256) khist2(const int* __restrict__ labels,
                                              int* __restrict__ hist) {
  __shared__ int h[NCLS];
  int t = threadIdx.x, s = blockIdx.x;
  h[t] = 0;
  __syncthreads();
  int base = s * SROWS + t;
#pragma unroll
  for (int k = 0; k < SROWS / 256; ++k) atomicAdd(&h[labels[base + k * 256]], 1);
  __syncthreads();
  hist[s * NCLS + t] = h[t];
}

// K2: per-strip deterministic scatter. Each strip block recomputes class bases
// (scan over all-strip totals) + its own strip prefix from hist; rows scatter
// via LDS cursors. Block 0 also publishes bases + float counts.
__global__ void __launch_bounds__(256) kscatter2(const int* __restrict__ labels,
                                                 const int* __restrict__ hist,
                                                 int* __restrict__ bases,
                                                 float* __restrict__ counts,
                                                 int* __restrict__ rowidx) {
  int t = threadIdx.x, s = blockIdx.x;  // t = class
  int run = 0, myoff = 0;
  for (int s2 = 0; s2 < NSTRIP; ++s2) {
    int h = hist[s2 * NCLS + t];        // coalesced across t
    if (s2 < s) myoff += h;
    run += h;
  }
  // exclusive scan of class totals
  __shared__ int sc[NCLS];
  sc[t] = run;
  __syncthreads();
  int v = sc[t];
  for (int off = 1; off < NCLS; off <<= 1) {
    int add = (t >= off) ? sc[t - off] : 0;
    __syncthreads();
    sc[t] = v = v + add;
    __syncthreads();
  }
  int excl = (t == 0) ? 0 : sc[t - 1];
  if (s == 0) {
    bases[t] = excl;
    counts[t] = (float)run;
  }
  __shared__ int loff[NCLS];
  __shared__ int cur[NCLS];
  loff[t] = excl + myoff;
  cur[t] = 0;
  __syncthreads();
  int rbase = s * SROWS + t;
#pragma unroll
  for (int k = 0; k < SROWS / 256; ++k) {
    int r = rbase + k * 256;
    int lab = labels[r];
    int lpos = atomicAdd(&cur[lab], 1);
    rowidx[loff[lab] + lpos] = r;
  }
}

// K3: fused row-norm + per-class segment sum; also emits normalized rows as
// packed bf16 (embn) for pass 2. Wave holds the 512-dim partial in 8 VGPRs.
__global__ void __launch_bounds__(256) ksumn(const float* __restrict__ emb,
                                             const int* __restrict__ rowidx,
                                             const int* __restrict__ bases,
                                             const float* __restrict__ counts,
                                             uint4* __restrict__ embn,
                                             float* __restrict__ partials) {
  int cls = blockIdx.x >> LSPL;
  int sp = blockIdx.x & ((1 << LSPL) - 1);
  int t = threadIdx.x, w = t >> 6, lane = t & 63;
  int base = bases[cls];
  int cnt = (int)counts[cls];
  int i0 = (cnt * sp) >> LSPL;
  int i1 = (cnt * (sp + 1)) >> LSPL;
  int n = i1 - i0;
  int j0 = i0 + ((n * w) >> 2);
  int j1 = i0 + ((n * (w + 1)) >> 2);
  const float4* ebase = reinterpret_cast<const float4*>(emb);
  int cq = lane * 2;  // float4 index: cols [lane*8, lane*8+8)
  float4 acc0 = make_float4(0.f, 0.f, 0.f, 0.f);
  float4 acc1 = make_float4(0.f, 0.f, 0.f, 0.f);
  int j = j0;
  for (; j + 4 <= j1; j += 4) {
    int r[4];
#pragma unroll
    for (int k = 0; k < 4; ++k) r[k] = rowidx[base + j + k];
    float4 a[4], b[4];
#pragma unroll
    for (int k = 0; k < 4; ++k) {
      const float4* p = ebase + (size_t)r[k] * (DIMS / 4) + cq;
      a[k] = p[0];
      b[k] = p[1];
    }
    float s[4];
#pragma unroll
    for (int k = 0; k < 4; ++k)
      s[k] = a[k].x*a[k].x + a[k].y*a[k].y + a[k].z*a[k].z + a[k].w*a[k].w
           + b[k].x*b[k].x + b[k].y*b[k].y + b[k].z*b[k].z + b[k].w*b[k].w;
#pragma unroll
    for (int off = 1; off < 64; off <<= 1) {
#pragma unroll
      for (int k = 0; k < 4; ++k) s[k] += __shfl_xor(s[k], off, 64);
    }
    float q[4];
#pragma unroll
    for (int k = 0; k < 4; ++k) q[k] = 1.0f / fmaxf(sqrtf(s[k]), EPSN);
#pragma unroll
    for (int k = 0; k < 4; ++k) {
      float nx0 = a[k].x * q[k], ny0 = a[k].y * q[k];
      float nz0 = a[k].z * q[k], nw0 = a[k].w * q[k];
      float nx1 = b[k].x * q[k], ny1 = b[k].y * q[k];
      float nz1 = b[k].z * q[k], nw1 = b[k].w * q[k];
      acc0.x += nx0; acc0.y += ny0; acc0.z += nz0; acc0.w += nw0;
      acc1.x += nx1; acc1.y += ny1; acc1.z += nz1; acc1.w += nw1;
      uint4 o;
      o.x = pk2(nx0, ny0); o.y = pk2(nz0, nw0);
      o.z = pk2(nx1, ny1); o.w = pk2(nz1, nw1);
      embn[(size_t)r[k] * (DIMS / 8) + lane] = o;
    }
  }
  for (; j < j1; ++j) {
    int r0 = rowidx[base + j];
    const float4* p = ebase + (size_t)r0 * (DIMS / 4) + cq;
    float4 a = p[0], b = p[1];
    float s = a.x*a.x + a.y*a.y + a.z*a.z + a.w*a.w
            + b.x*b.x + b.y*b.y + b.z*b.z + b.w*b.w;
#pragma unroll
    for (int off = 1; off < 64; off <<= 1) s += __shfl_xor(s, off, 64);
    float q0 = 1.0f / fmaxf(sqrtf(s), EPSN);
    float nx0 = a.x*q0, ny0 = a.y*q0, nz0 = a.z*q0, nw0 = a.w*q0;
    float nx1 = b.x*q0, ny1 = b.y*q0, nz1 = b.z*q0, nw1 = b.w*q0;
    acc0.x += nx0; acc0.y += ny0; acc0.z += nz0; acc0.w += nw0;
    acc1.x += nx1; acc1.y += ny1; acc1.z += nz1; acc1.w += nw1;
    uint4 o;
    o.x = pk2(nx0, ny0); o.y = pk2(nz0, nw0);
    o.z = pk2(nx1, ny1); o.w = pk2(nz1, nw1);
    embn[(size_t)r0 * (DIMS / 8) + lane] = o;
  }
  __shared__ float lds[4][DIMS];
  *reinterpret_cast<float4*>(&lds[w][lane * 8]) = acc0;
  *reinterpret_cast<float4*>(&lds[w][lane * 8 + 4]) = acc1;
  __syncthreads();
  float o0 = lds[0][t] + lds[1][t] + lds[2][t] + lds[3][t];
  float o1 = lds[0][t + 256] + lds[1][t + 256] + lds[2][t + 256] + lds[3][t + 256];
  float* outp = partials + ((size_t)sp * NCLS + cls) * DIMS;
  outp[t] = o0;
  outp[t + 256] = o1;
}

// K4: reduce split partials -> mean -> L2-normalized centroid.
__global__ void __launch_bounds__(256) kcent(const float* __restrict__ partials,
                                             const float* __restrict__ counts,
                                             float* __restrict__ cent) {
  int cls = blockIdx.x, t = threadIdx.x;
  float s0 = 0.0f, s1 = 0.0f;
#pragma unroll
  for (int sp = 0; sp < (1 << LSPL); ++sp) {
    const float* p = partials + ((size_t)sp * NCLS + cls) * DIMS;
    s0 += p[t];
    s1 += p[t + 256];
  }
  float cm = fmaxf(counts[cls], 1.0f);
  float m0 = s0 / cm, m1 = s1 / cm;
  __shared__ float red[256];
  red[t] = m0 * m0 + m1 * m1;
  __syncthreads();
  for (int off = 128; off > 0; off >>= 1) {
    if (t < off) red[t] += red[t + off];
    __syncthreads();
  }
  float inv = 1.0f / fmaxf(sqrtf(red[0]), EPSN);
  cent[(size_t)cls * DIMS + t] = m0 * inv;
  cent[(size_t)cls * DIMS + t + 256] = m1 * inv;
}

// K5: nearest-centroid argmin (lexicographic ties = jnp.argmin).
__global__ void __launch_bounds__(256) knearest(const float* __restrict__ cent,
                                                const float* __restrict__ counts,
                                                int* __restrict__ nearest) {
  int i = blockIdx.x, j = threadIdx.x;
  __shared__ float ci[DIMS];
  ci[j] = cent[(size_t)i * DIMS + j];
  ci[j + 256] = cent[(size_t)i * DIMS + j + 256];
  __syncthreads();
  const float4* cj = reinterpret_cast<const float4*>(cent + (size_t)j * DIMS);
  float dot = 0.0f;
#pragma unroll 8
  for (int k = 0; k < DIMS / 4; ++k) {
    float4 v = cj[k];
    dot += v.x * ci[4*k] + v.y * ci[4*k+1] + v.z * ci[4*k+2] + v.w * ci[4*k+3];
  }
  float dist = sqrtf(fmaxf(2.0f - 2.0f * dot, 0.0f));
  bool valid = (j != i) && (counts[j] > 0.0f);
  float dv = valid ? dist : INFINITY;
  __shared__ float sd[256];
  __shared__ int si[256];
  sd[j] = dv; si[j] = j;
  __syncthreads();
  for (int off = 128; off > 0; off >>= 1) {
    if (j < off) {
      float o = sd[j + off]; int oi = si[j + off];
      if (o < sd[j] || (o == sd[j] && oi < si[j])) { sd[j] = o; si[j] = oi; }
    }
    __syncthreads();
  }
  if (j == 0) nearest[i] = si[0];
}

// K6: triplet terms from bf16 normalized rows (L3-hot, 1 uint4/row/lane).
// diff = neg_c - pos_c in registers (block-uniform class); 8-row unroll.
__global__ void __launch_bounds__(256) kterm2(const uint4* __restrict__ embn,
                                              const int* __restrict__ rowidx,
                                              const int* __restrict__ bases,
                                              const float* __restrict__ counts,
                                              const float* __restrict__ cent,
                                              const int* __restrict__ nearest,
                                              float* __restrict__ tsums) {
  int cls = blockIdx.x >> 3;  // TSPL == 8
  int sp = blockIdx.x & (TSPL - 1);
  int t = threadIdx.x, w = t >> 6, lane = t & 63;
  int base = bases[cls];
  int cnt = (int)counts[cls];
  int ng = nearest[cls];
  int cq = lane * 2;
  const float4* pp = reinterpret_cast<const float4*>(cent + (size_t)cls * DIMS) + cq;
  const float4* pn = reinterpret_cast<const float4*>(cent + (size_t)ng * DIMS) + cq;
  float4 P0 = pp[0], P1 = pp[1], N0 = pn[0], N1 = pn[1];
  float4 d0 = make_float4(N0.x - P0.x, N0.y - P0.y, N0.z - P0.z, N0.w - P0.w);
  float4 d1 = make_float4(N1.x - P1.x, N1.y - P1.y, N1.z - P1.z, N1.w - P1.w);
  int i0 = (cnt * sp) / TSPL;
  int i1 = (cnt * (sp + 1)) / TSPL;
  int n = i1 - i0;
  int j0 = i0 + ((n * w) >> 2);
  int j1 = i0 + ((n * (w + 1)) >> 2);
  float tsum = 0.0f;
  int j = j0;
  for (; j + 8 <= j1; j += 8) {
    int r[8];
#pragma unroll
    for (int k = 0; k < 8; ++k) r[k] = rowidx[base + j + k];
    uint4 v[8];
#pragma unroll
    for (int k = 0; k < 8; ++k) v[k] = embn[(size_t)r[k] * (DIMS / 8) + lane];
    float s[8];
#pragma unroll
    for (int k = 0; k < 8; ++k)
      s[k] = uplo(v[k].x)*d0.x + uphi(v[k].x)*d0.y + uplo(v[k].y)*d0.z + uphi(v[k].y)*d0.w
           + uplo(v[k].z)*d1.x + uphi(v[k].z)*d1.y + uplo(v[k].w)*d1.z + uphi(v[k].w)*d1.w;
#pragma unroll
    for (int off = 1; off < 64; off <<= 1) {
#pragma unroll
      for (int k = 0; k < 8; ++k) s[k] += __shfl_xor(s[k], off, 64);
    }
#pragma unroll
    for (int k = 0; k < 8; ++k) tsum += fmaxf(s[k] + MARGIN, 0.0f);
  }
  for (; j < j1; ++j) {
    int r0 = rowidx[base + j];
    uint4 v = embn[(size_t)r0 * (DIMS / 8) + lane];
    float s = uplo(v.x)*d0.x + uphi(v.x)*d0.y + uplo(v.y)*d0.z + uphi(v.y)*d0.w
            + uplo(v.z)*d1.x + uphi(v.z)*d1.y + uplo(v.w)*d1.z + uphi(v.w)*d1.w;
#pragma unroll
    for (int off = 1; off < 64; off <<= 1) s += __shfl_xor(s, off, 64);
    tsum += fmaxf(s + MARGIN, 0.0f);
  }
  __shared__ float sred[4];
  if (lane == 0) sred[w] = tsum;
  __syncthreads();
  if (t == 0) tsums[blockIdx.x] = sred[0] + sred[1] + sred[2] + sred[3];
}

// K7: final present-masked mean of per-class means.
__global__ void __launch_bounds__(256) kfinal(const float* __restrict__ counts,
                                              const float* __restrict__ tsums,
                                              float* __restrict__ out) {
  int t = threadIdx.x;
  float cnt = counts[t];
  bool present = cnt > 0.0f;
  float ls = 0.0f;
#pragma unroll
  for (int k = 0; k < TSPL; ++k) ls += tsums[t * TSPL + k];
  float v = present ? ls / fmaxf(cnt, 1.0f) : 0.0f;
  float np = present ? 1.0f : 0.0f;
  __shared__ float sv[256], sp[256];
  sv[t] = v; sp[t] = np;
  __syncthreads();
  for (int off = 128; off > 0; off >>= 1) {
    if (t < off) { sv[t] += sv[t + off]; sp[t] += sp[t + off]; }
    __syncthreads();
  }
  if (t == 0) out[0] = sv[0] / fmaxf(sp[0], 1.0f);
}

extern "C" void kernel_launch(void* const* d_in, const int* in_sizes, int n_in,
                              void* d_out, int out_size, void* d_ws, size_t ws_size,
                              hipStream_t stream) {
  const float* emb = (const float*)d_in[0];
  const int* labels = (const int*)d_in[1];
  float* out = (float*)d_out;

  char* ws = (char*)d_ws;
  size_t off = 0;
  auto alloc = [&](size_t bytes) {
    char* p = ws + off;
    off += (bytes + 255) & ~(size_t)255;
    return p;
  };
  int*   hist    = (int*)alloc((size_t)NSTRIP * NCLS * 4);            // 64 KB
  int*   bases   = (int*)alloc((size_t)NCLS * 4);                     // 1 KB
  float* counts  = (float*)alloc((size_t)NCLS * 4);                   // 1 KB
  float* cent    = (float*)alloc((size_t)NCLS * DIMS * 4);            // 512 KB
  int*   nearest = (int*)alloc((size_t)NCLS * 4);                     // 1 KB
  int*   rowidx  = (int*)alloc((size_t)BROWS * 4);                    // 256 KB
  float* tsums   = (float*)alloc((size_t)NCLS * TSPL * 4);            // 8 KB
  float* partials= (float*)alloc(((size_t)NCLS * DIMS * 4) << LSPL);  // 4 MB
  uint4* embn    = (uint4*)alloc((size_t)BROWS * DIMS * 2);           // 64 MB (bf16)

  khist2<<<NSTRIP, 256, 0, stream>>>(labels, hist);
  kscatter2<<<NSTRIP, 256, 0, stream>>>(labels, hist, bases, counts, rowidx);
  ksumn<<<NCLS << LSPL, 256, 0, stream>>>(emb, rowidx, bases, counts, embn, partials);
  kcent<<<NCLS, 256, 0, stream>>>(partials, counts, cent);
  knearest<<<NCLS, 256, 0, stream>>>(cent, counts, nearest);
  kterm2<<<NCLS * TSPL, 256, 0, stream>>>(embn, rowidx, bases, counts, cent, nearest, tsums);
  kfinal<<<1, 256, 0, stream>>>(counts, tsums, out);
}

// Round 9
// 247.834 us; speedup vs baseline: 2.2628x; 1.0210x over previous
//
#include <hip/hip_runtime.h>
#include <math.h>

#define BROWS 65536
#define DIMS 512
#define NCLS 256
#define MARGIN 0.3f
#define EPSN 1e-12f
#define NSTRIP 64      // 64 strips x 1024 rows
#define SROWS 1024
#define LSPL 3         // 8 splits/class in ksumn
#define TSPL 8         // 8 splits/class in kterm2

// K1: per-strip label histogram (LDS atomics only).
__global__ void __launch_bounds__(256) khist2(const int* __restrict__ labels,
                                              int* __restrict__ hist) {
  __shared__ int h[NCLS];
  int t = threadIdx.x, s = blockIdx.x;
  h[t] = 0;
  __syncthreads();
  int base = s * SROWS + t;
#pragma unroll
  for (int k = 0; k < SROWS / 256; ++k) atomicAdd(&h[labels[base + k * 256]], 1);
  __syncthreads();
  hist[s * NCLS + t] = h[t];
}

// K2: per-strip deterministic scatter. Each strip block recomputes class bases
// (scan over all-strip totals) + its own strip prefix from hist; rows scatter
// via LDS cursors. Block 0 also publishes bases + float counts.
__global__ void __launch_bounds__(256) kscatter2(const int* __restrict__ labels,
                                                 const int* __restrict__ hist,
                                                 int* __restrict__ bases,
                                                 float* __restrict__ counts,
                                                 int* __restrict__ rowidx) {
  int t = threadIdx.x, s = blockIdx.x;  // t = class
  int run = 0, myoff = 0;
  for (int s2 = 0; s2 < NSTRIP; ++s2) {
    int h = hist[s2 * NCLS + t];        // coalesced across t
    if (s2 < s) myoff += h;
    run += h;
  }
  // exclusive scan of class totals
  __shared__ int sc[NCLS];
  sc[t] = run;
  __syncthreads();
  int v = sc[t];
  for (int off = 1; off < NCLS; off <<= 1) {
    int add = (t >= off) ? sc[t - off] : 0;
    __syncthreads();
    sc[t] = v = v + add;
    __syncthreads();
  }
  int excl = (t == 0) ? 0 : sc[t - 1];
  if (s == 0) {
    bases[t] = excl;
    counts[t] = (float)run;
  }
  __shared__ int loff[NCLS];
  __shared__ int cur[NCLS];
  loff[t] = excl + myoff;
  cur[t] = 0;
  __syncthreads();
  int rbase = s * SROWS + t;
#pragma unroll
  for (int k = 0; k < SROWS / 256; ++k) {
    int r = rbase + k * 256;
    int lab = labels[r];
    int lpos = atomicAdd(&cur[lab], 1);
    rowidx[loff[lab] + lpos] = r;
  }
}

// K3: fused row-norm + per-class segment sum of normalized rows (lean: no
// bf16 emission). Wave holds the 512-dim partial in 8 VGPRs/lane; 4-row
// unroll keeps 8 independent dwordx4 loads in flight.
__global__ void __launch_bounds__(256) ksumn(const float* __restrict__ emb,
                                             const int* __restrict__ rowidx,
                                             const int* __restrict__ bases,
                                             const float* __restrict__ counts,
                                             float* __restrict__ invnorm,
                                             float* __restrict__ partials) {
  int cls = blockIdx.x >> LSPL;
  int sp = blockIdx.x & ((1 << LSPL) - 1);
  int t = threadIdx.x, w = t >> 6, lane = t & 63;
  int base = bases[cls];
  int cnt = (int)counts[cls];
  int i0 = (cnt * sp) >> LSPL;
  int i1 = (cnt * (sp + 1)) >> LSPL;
  int n = i1 - i0;
  int j0 = i0 + ((n * w) >> 2);
  int j1 = i0 + ((n * (w + 1)) >> 2);
  const float4* ebase = reinterpret_cast<const float4*>(emb);
  int cq = lane * 2;  // float4 index: cols [lane*8, lane*8+8)
  float4 acc0 = make_float4(0.f, 0.f, 0.f, 0.f);
  float4 acc1 = make_float4(0.f, 0.f, 0.f, 0.f);
  int j = j0;
  for (; j + 4 <= j1; j += 4) {
    int r[4];
#pragma unroll
    for (int k = 0; k < 4; ++k) r[k] = rowidx[base + j + k];
    float4 a[4], b[4];
#pragma unroll
    for (int k = 0; k < 4; ++k) {
      const float4* p = ebase + (size_t)r[k] * (DIMS / 4) + cq;
      a[k] = p[0];
      b[k] = p[1];
    }
    float s[4];
#pragma unroll
    for (int k = 0; k < 4; ++k)
      s[k] = a[k].x*a[k].x + a[k].y*a[k].y + a[k].z*a[k].z + a[k].w*a[k].w
           + b[k].x*b[k].x + b[k].y*b[k].y + b[k].z*b[k].z + b[k].w*b[k].w;
#pragma unroll
    for (int off = 1; off < 64; off <<= 1) {
#pragma unroll
      for (int k = 0; k < 4; ++k) s[k] += __shfl_xor(s[k], off, 64);
    }
    float q[4];
#pragma unroll
    for (int k = 0; k < 4; ++k) q[k] = 1.0f / fmaxf(sqrtf(s[k]), EPSN);
    if (lane == 0) {
      invnorm[r[0]] = q[0]; invnorm[r[1]] = q[1];
      invnorm[r[2]] = q[2]; invnorm[r[3]] = q[3];
    }
#pragma unroll
    for (int k = 0; k < 4; ++k) {
      acc0.x += a[k].x * q[k]; acc0.y += a[k].y * q[k];
      acc0.z += a[k].z * q[k]; acc0.w += a[k].w * q[k];
      acc1.x += b[k].x * q[k]; acc1.y += b[k].y * q[k];
      acc1.z += b[k].z * q[k]; acc1.w += b[k].w * q[k];
    }
  }
  for (; j < j1; ++j) {
    int r0 = rowidx[base + j];
    const float4* p = ebase + (size_t)r0 * (DIMS / 4) + cq;
    float4 a = p[0], b = p[1];
    float s = a.x*a.x + a.y*a.y + a.z*a.z + a.w*a.w
            + b.x*b.x + b.y*b.y + b.z*b.z + b.w*b.w;
#pragma unroll
    for (int off = 1; off < 64; off <<= 1) s += __shfl_xor(s, off, 64);
    float q0 = 1.0f / fmaxf(sqrtf(s), EPSN);
    if (lane == 0) invnorm[r0] = q0;
    acc0.x += a.x * q0; acc0.y += a.y * q0; acc0.z += a.z * q0; acc0.w += a.w * q0;
    acc1.x += b.x * q0; acc1.y += b.y * q0; acc1.z += b.z * q0; acc1.w += b.w * q0;
  }
  __shared__ float lds[4][DIMS];
  *reinterpret_cast<float4*>(&lds[w][lane * 8]) = acc0;
  *reinterpret_cast<float4*>(&lds[w][lane * 8 + 4]) = acc1;
  __syncthreads();
  float o0 = lds[0][t] + lds[1][t] + lds[2][t] + lds[3][t];
  float o1 = lds[0][t + 256] + lds[1][t + 256] + lds[2][t + 256] + lds[3][t + 256];
  float* outp = partials + ((size_t)sp * NCLS + cls) * DIMS;
  outp[t] = o0;
  outp[t + 256] = o1;
}

// K4: reduce split partials -> mean -> L2-normalized centroid.
__global__ void __launch_bounds__(256) kcent(const float* __restrict__ partials,
                                             const float* __restrict__ counts,
                                             float* __restrict__ cent) {
  int cls = blockIdx.x, t = threadIdx.x;
  float s0 = 0.0f, s1 = 0.0f;
#pragma unroll
  for (int sp = 0; sp < (1 << LSPL); ++sp) {
    const float* p = partials + ((size_t)sp * NCLS + cls) * DIMS;
    s0 += p[t];
    s1 += p[t + 256];
  }
  float cm = fmaxf(counts[cls], 1.0f);
  float m0 = s0 / cm, m1 = s1 / cm;
  __shared__ float red[256];
  red[t] = m0 * m0 + m1 * m1;
  __syncthreads();
  for (int off = 128; off > 0; off >>= 1) {
    if (t < off) red[t] += red[t + off];
    __syncthreads();
  }
  float inv = 1.0f / fmaxf(sqrtf(red[0]), EPSN);
  cent[(size_t)cls * DIMS + t] = m0 * inv;
  cent[(size_t)cls * DIMS + t + 256] = m1 * inv;
}

// K5: nearest-centroid argmin (lexicographic ties = jnp.argmin).
__global__ void __launch_bounds__(256) knearest(const float* __restrict__ cent,
                                                const float* __restrict__ counts,
                                                int* __restrict__ nearest) {
  int i = blockIdx.x, j = threadIdx.x;
  __shared__ float ci[DIMS];
  ci[j] = cent[(size_t)i * DIMS + j];
  ci[j + 256] = cent[(size_t)i * DIMS + j + 256];
  __syncthreads();
  const float4* cj = reinterpret_cast<const float4*>(cent + (size_t)j * DIMS);
  float dot = 0.0f;
#pragma unroll 8
  for (int k = 0; k < DIMS / 4; ++k) {
    float4 v = cj[k];
    dot += v.x * ci[4*k] + v.y * ci[4*k+1] + v.z * ci[4*k+2] + v.w * ci[4*k+3];
  }
  float dist = sqrtf(fmaxf(2.0f - 2.0f * dot, 0.0f));
  bool valid = (j != i) && (counts[j] > 0.0f);
  float dv = valid ? dist : INFINITY;
  __shared__ float sd[256];
  __shared__ int si[256];
  sd[j] = dv; si[j] = j;
  __syncthreads();
  for (int off = 128; off > 0; off >>= 1) {
    if (j < off) {
      float o = sd[j + off]; int oi = si[j + off];
      if (o < sd[j] || (o == sd[j] && oi < si[j])) { sd[j] = o; si[j] = oi; }
    }
    __syncthreads();
  }
  if (j == 0) nearest[i] = si[0];
}

// K6: triplet terms from raw f32 emb (L3-hot after ksumn).
// term = relu(dot(emb_row, neg_c - pos_c) * invnorm + margin).
// diff in registers (block-uniform class); 4-row unroll; no atomics.
__global__ void __launch_bounds__(256) kterm2(const float* __restrict__ emb,
                                              const float* __restrict__ invnorm,
                                              const int* __restrict__ rowidx,
                                              const int* __restrict__ bases,
                                              const float* __restrict__ counts,
                                              const float* __restrict__ cent,
                                              const int* __restrict__ nearest,
                                              float* __restrict__ tsums) {
  int cls = blockIdx.x >> 3;  // TSPL == 8
  int sp = blockIdx.x & (TSPL - 1);
  int t = threadIdx.x, w = t >> 6, lane = t & 63;
  int base = bases[cls];
  int cnt = (int)counts[cls];
  int ng = nearest[cls];
  int cq = lane * 2;
  const float4* pp = reinterpret_cast<const float4*>(cent + (size_t)cls * DIMS) + cq;
  const float4* pn = reinterpret_cast<const float4*>(cent + (size_t)ng * DIMS) + cq;
  float4 P0 = pp[0], P1 = pp[1], N0 = pn[0], N1 = pn[1];
  float4 d0 = make_float4(N0.x - P0.x, N0.y - P0.y, N0.z - P0.z, N0.w - P0.w);
  float4 d1 = make_float4(N1.x - P1.x, N1.y - P1.y, N1.z - P1.z, N1.w - P1.w);
  int i0 = (cnt * sp) / TSPL;
  int i1 = (cnt * (sp + 1)) / TSPL;
  int n = i1 - i0;
  int j0 = i0 + ((n * w) >> 2);
  int j1 = i0 + ((n * (w + 1)) >> 2);
  const float4* ebase = reinterpret_cast<const float4*>(emb);
  float tsum = 0.0f;
  int j = j0;
  for (; j + 4 <= j1; j += 4) {
    int r[4];
#pragma unroll
    for (int k = 0; k < 4; ++k) r[k] = rowidx[base + j + k];
    float inv[4];
#pragma unroll
    for (int k = 0; k < 4; ++k) inv[k] = invnorm[r[k]];
    float4 a[4], b[4];
#pragma unroll
    for (int k = 0; k < 4; ++k) {
      const float4* p = ebase + (size_t)r[k] * (DIMS / 4) + cq;
      a[k] = p[0];
      b[k] = p[1];
    }
    float s[4];
#pragma unroll
    for (int k = 0; k < 4; ++k)
      s[k] = a[k].x*d0.x + a[k].y*d0.y + a[k].z*d0.z + a[k].w*d0.w
           + b[k].x*d1.x + b[k].y*d1.y + b[k].z*d1.z + b[k].w*d1.w;
#pragma unroll
    for (int off = 1; off < 64; off <<= 1) {
#pragma unroll
      for (int k = 0; k < 4; ++k) s[k] += __shfl_xor(s[k], off, 64);
    }
#pragma unroll
    for (int k = 0; k < 4; ++k) tsum += fmaxf(s[k] * inv[k] + MARGIN, 0.0f);
  }
  for (; j < j1; ++j) {
    int r0 = rowidx[base + j];
    float inv0 = invnorm[r0];
    const float4* p = ebase + (size_t)r0 * (DIMS / 4) + cq;
    float4 a = p[0], b = p[1];
    float s = a.x*d0.x + a.y*d0.y + a.z*d0.z + a.w*d0.w
            + b.x*d1.x + b.y*d1.y + b.z*d1.z + b.w*d1.w;
#pragma unroll
    for (int off = 1; off < 64; off <<= 1) s += __shfl_xor(s, off, 64);
    tsum += fmaxf(s * inv0 + MARGIN, 0.0f);
  }
  __shared__ float sred[4];
  if (lane == 0) sred[w] = tsum;
  __syncthreads();
  if (t == 0) tsums[blockIdx.x] = sred[0] + sred[1] + sred[2] + sred[3];
}

// K7: final present-masked mean of per-class means.
__global__ void __launch_bounds__(256) kfinal(const float* __restrict__ counts,
                                              const float* __restrict__ tsums,
                                              float* __restrict__ out) {
  int t = threadIdx.x;
  float cnt = counts[t];
  bool present = cnt > 0.0f;
  float ls = 0.0f;
#pragma unroll
  for (int k = 0; k < TSPL; ++k) ls += tsums[t * TSPL + k];
  float v = present ? ls / fmaxf(cnt, 1.0f) : 0.0f;
  float np = present ? 1.0f : 0.0f;
  __shared__ float sv[256], sp[256];
  sv[t] = v; sp[t] = np;
  __syncthreads();
  for (int off = 128; off > 0; off >>= 1) {
    if (t < off) { sv[t] += sv[t + off]; sp[t] += sp[t + off]; }
    __syncthreads();
  }
  if (t == 0) out[0] = sv[0] / fmaxf(sp[0], 1.0f);
}

extern "C" void kernel_launch(void* const* d_in, const int* in_sizes, int n_in,
                              void* d_out, int out_size, void* d_ws, size_t ws_size,
                              hipStream_t stream) {
  const float* emb = (const float*)d_in[0];
  const int* labels = (const int*)d_in[1];
  float* out = (float*)d_out;

  char* ws = (char*)d_ws;
  size_t off = 0;
  auto alloc = [&](size_t bytes) {
    char* p = ws + off;
    off += (bytes + 255) & ~(size_t)255;
    return p;
  };
  int*   hist    = (int*)alloc((size_t)NSTRIP * NCLS * 4);            // 64 KB
  int*   bases   = (int*)alloc((size_t)NCLS * 4);                     // 1 KB
  float* counts  = (float*)alloc((size_t)NCLS * 4);                   // 1 KB
  float* cent    = (float*)alloc((size_t)NCLS * DIMS * 4);            // 512 KB
  int*   nearest = (int*)alloc((size_t)NCLS * 4);                     // 1 KB
  int*   rowidx  = (int*)alloc((size_t)BROWS * 4);                    // 256 KB
  float* invnorm = (float*)alloc((size_t)BROWS * 4);                  // 256 KB
  float* tsums   = (float*)alloc((size_t)NCLS * TSPL * 4);            // 8 KB
  float* partials= (float*)alloc(((size_t)NCLS * DIMS * 4) << LSPL);  // 4 MB

  khist2<<<NSTRIP, 256, 0, stream>>>(labels, hist);
  kscatter2<<<NSTRIP, 256, 0, stream>>>(labels, hist, bases, counts, rowidx);
  ksumn<<<NCLS << LSPL, 256, 0, stream>>>(emb, rowidx, bases, counts, invnorm, partials);
  kcent<<<NCLS, 256, 0, stream>>>(partials, counts, cent);
  knearest<<<NCLS, 256, 0, stream>>>(cent, counts, nearest);
  kterm2<<<NCLS * TSPL, 256, 0, stream>>>(emb, invnorm, rowidx, bases, counts,
                                          cent, nearest, tsums);
  kfinal<<<1, 256, 0, stream>>>(counts, tsums, out);
}